// Round 13
// baseline (367.666 us; speedup 1.0000x reference)
//
#include <hip/hip_runtime.h>
#include <hip/hip_fp16.h>
#include <math.h>

#define N_NODES 100000
#define N_EDGES 3200000
#define N_GRAPHS 512

#define BSHIFT 7
#define BSPAN 128                      // nodes per bucket
#define NB 782                         // ceil(N_NODES / BSPAN)
#define SLACK 4800                     // bucket capacity (mean 4096 + ~11 sigma)
#define SBLK 4096                      // edges per scatter block
#define SBLOCKS ((N_EDGES + SBLK - 1) / SBLK)   // 782

typedef float floatx2 __attribute__((ext_vector_type(2)));
typedef float floatx4 __attribute__((ext_vector_type(4)));
typedef int   intx4   __attribute__((ext_vector_type(4)));

// ---------- setup: cursors + Wz fold + pooled2 zero (one dispatch) ----------
__global__ __launch_bounds__(256) void setup_kernel(const float* __restrict__ W2,
                                                    const float* __restrict__ b2,
                                                    const float* __restrict__ Wl1,
                                                    const float* __restrict__ bl1,
                                                    const float* __restrict__ Wl2,
                                                    const float* __restrict__ bl2,
                                                    int* __restrict__ cursor,
                                                    float* __restrict__ Wz,
                                                    float* __restrict__ zc,
                                                    float* __restrict__ pooled2) {
    __shared__ float Weff[64 * 2];
    int tid = threadIdx.x;
    for (int i = tid; i < NB; i += 256) cursor[i] = i * SLACK;
    for (int i = tid; i < N_GRAPHS * 2; i += 256) pooled2[i] = 0.f;
    if (tid < 128) {
        int c = tid >> 1, j = tid & 1;
        float s = 0.f;
        for (int k = 0; k < 32; ++k) s += Wl1[c * 32 + k] * Wl2[k * 2 + j];
        Weff[c * 2 + j] = s;
    }
    __syncthreads();
    if (tid < 128) {
        int i = tid >> 1, j = tid & 1;
        float s = 0.f;
        for (int c = 0; c < 64; ++c) s += W2[i * 64 + c] * Weff[c * 2 + j];
        Wz[i * 2 + j] = s;
    }
    if (tid < 2) {
        float s = bl2[tid];
        for (int k = 0; k < 32; ++k) s += bl1[k] * Wl2[k * 2 + tid];
        for (int c = 0; c < 64; ++c) s += b2[c] * Weff[c * 2 + tid];
        zc[tid] = s;
    }
}

// ---------- scatter3: register-staged single-pass histogram+reserve+scatter ----------
__global__ __launch_bounds__(256) void scatter3_kernel(const int* __restrict__ src,
                                                       const int* __restrict__ dst,
                                                       int* __restrict__ cursor,
                                                       unsigned int* __restrict__ pairs, int E) {
    __shared__ int hcnt[NB];
    __shared__ int hbase[NB];
    int tid = threadIdx.x;
    for (int b = tid; b < NB; b += 256) hcnt[b] = 0;
    __syncthreads();
    int base = blockIdx.x * SBLK;
    int end = min(E, base + SBLK);
    intx4 dv[4], sv[4];
    int rk[16];
    bool ok[4];
#pragma unroll
    for (int k = 0; k < 4; ++k) {
        int e = base + tid * 4 + k * 1024;
        ok[k] = (e < end);                      // 4-aligned block sizes -> whole int4 in or out
        if (ok[k]) {
            dv[k] = __builtin_nontemporal_load(reinterpret_cast<const intx4*>(&dst[e]));
            sv[k] = __builtin_nontemporal_load(reinterpret_cast<const intx4*>(&src[e]));
        }
    }
#pragma unroll
    for (int k = 0; k < 4; ++k) {
        if (ok[k]) {
            rk[4 * k + 0] = atomicAdd(&hcnt[dv[k].x >> BSHIFT], 1);
            rk[4 * k + 1] = atomicAdd(&hcnt[dv[k].y >> BSHIFT], 1);
            rk[4 * k + 2] = atomicAdd(&hcnt[dv[k].z >> BSHIFT], 1);
            rk[4 * k + 3] = atomicAdd(&hcnt[dv[k].w >> BSHIFT], 1);
        }
    }
    __syncthreads();
    for (int b = tid; b < NB; b += 256) {
        int c = hcnt[b];
        if (c) hbase[b] = atomicAdd(&cursor[b], c);
    }
    __syncthreads();
#pragma unroll
    for (int k = 0; k < 4; ++k) {
        if (ok[k]) {
            __builtin_nontemporal_store(
                ((unsigned int)sv[k].x << BSHIFT) | (unsigned int)(dv[k].x & (BSPAN - 1)),
                &pairs[hbase[dv[k].x >> BSHIFT] + rk[4 * k + 0]]);
            __builtin_nontemporal_store(
                ((unsigned int)sv[k].y << BSHIFT) | (unsigned int)(dv[k].y & (BSPAN - 1)),
                &pairs[hbase[dv[k].y >> BSHIFT] + rk[4 * k + 1]]);
            __builtin_nontemporal_store(
                ((unsigned int)sv[k].z << BSHIFT) | (unsigned int)(dv[k].z & (BSPAN - 1)),
                &pairs[hbase[dv[k].z >> BSHIFT] + rk[4 * k + 2]]);
            __builtin_nontemporal_store(
                ((unsigned int)sv[k].w << BSHIFT) | (unsigned int)(dv[k].w & (BSPAN - 1)),
                &pairs[hbase[dv[k].w >> BSHIFT] + rk[4 * k + 3]]);
        }
    }
}

// ---------- bucket: per-bucket fine sort -> col (src<<3), bele(beg,end), dinv ----------
__global__ __launch_bounds__(256) void bucket_kernel(const unsigned int* __restrict__ pairs,
                                                     const int* __restrict__ cursor,
                                                     int* __restrict__ col,
                                                     int2* __restrict__ bele,
                                                     float* __restrict__ dinv, int N) {
    __shared__ int ncnt[BSPAN];
    __shared__ int nbase[BSPAN];
    __shared__ int a[BSPAN];
    int b = blockIdx.x, tid = threadIdx.x;
    int base = b * SLACK;
    int cntb = cursor[b] - base;
    int n0 = b << BSHIFT;
    int nn = min(BSPAN, N - n0);
    if (tid < BSPAN) ncnt[tid] = 0;
    __syncthreads();
    for (int i = tid; i < cntb; i += 256)
        atomicAdd(&ncnt[pairs[base + i] & (BSPAN - 1)], 1);
    __syncthreads();
    if (tid < BSPAN) a[tid] = ncnt[tid];
    __syncthreads();
    for (int st = 1; st < BSPAN; st <<= 1) {
        int t = (tid < BSPAN && tid >= st) ? a[tid - st] : 0;
        __syncthreads();
        if (tid < BSPAN) a[tid] += t;
        __syncthreads();
    }
    if (tid < BSPAN) {
        int v = ncnt[tid];
        int excl = a[tid] - v;
        nbase[tid] = excl;
        if (tid < nn) {
            int beg = base + excl;
            bele[n0 + tid] = make_int2(beg, beg + v);
            dinv[n0 + tid] = rsqrtf((float)(v + 1));   // +1 self loop
        }
        ncnt[tid] = 0;   // reuse as cursor
    }
    __syncthreads();
    for (int i = tid; i < cntb; i += 256) {
        unsigned int p = pairs[base + i];
        int dl = p & (BSPAN - 1);
        int pos = base + nbase[dl] + atomicAdd(&ncnt[dl], 1);
        __builtin_nontemporal_store((int)(p >> BSHIFT) << 3, &col[pos]);
    }
}

// ---------- dense linear: U[n,64] = fp8(dinv[n] * (X[n,K] @ W[K,64])) ----------
template <int K>
__global__ __launch_bounds__(256) void lin_kernel(const float* __restrict__ X,
                                                  const float* __restrict__ W,
                                                  const float* __restrict__ rs,
                                                  unsigned char* __restrict__ U) {
    __shared__ float Ws[K * 64];
    __shared__ float Xs[32 * K];
    int tid = threadIdx.x;
    for (int i = tid * 4; i < K * 64; i += 256 * 4)
        *reinterpret_cast<float4*>(&Ws[i]) = *reinterpret_cast<const float4*>(&W[i]);
    int row0 = blockIdx.x * 32;
    const float* Xbase = X + (size_t)row0 * K;
    for (int i = tid * 4; i < 32 * K; i += 256 * 4)
        *reinterpret_cast<floatx4*>(&Xs[i]) =
            __builtin_nontemporal_load(reinterpret_cast<const floatx4*>(&Xbase[i]));
    __syncthreads();

    int wid = tid >> 6, lane = tid & 63;
    int rbase = wid * 8;
    float acc[8];
#pragma unroll
    for (int r = 0; r < 8; ++r) acc[r] = 0.f;

    for (int k4 = 0; k4 < K / 4; ++k4) {
        float w0 = Ws[(k4 * 4 + 0) * 64 + lane];
        float w1 = Ws[(k4 * 4 + 1) * 64 + lane];
        float w2 = Ws[(k4 * 4 + 2) * 64 + lane];
        float w3 = Ws[(k4 * 4 + 3) * 64 + lane];
#pragma unroll
        for (int r = 0; r < 8; ++r) {
            float4 xv = *reinterpret_cast<const float4*>(&Xs[(rbase + r) * K + k4 * 4]);
            acc[r] += xv.x * w0 + xv.y * w1 + xv.z * w2 + xv.w * w3;
        }
    }
#pragma unroll
    for (int r = 0; r < 8; ++r) {
        int row = row0 + rbase + r;
        float v = acc[r] * rs[row];
        int pk = __builtin_amdgcn_cvt_pk_fp8_f32(v, v, 0, false);
        U[(size_t)row * 64 + lane] = (unsigned char)(pk & 0xff);
    }
}

// ---------- agg1: wave = node, 8 lanes/edge x 8 strided edge slots, fp8 gathers,
// packed f32 accum, nontemporal col stream. Epilogue (r==0): relu+bias, @Wz, qz. ----------
#define ACC8(a)                                                                  \
    {                                                                            \
        acc2[0] += __builtin_amdgcn_cvt_pk_f32_fp8((int)(a).x, false);           \
        acc2[1] += __builtin_amdgcn_cvt_pk_f32_fp8((int)(a).x, true);            \
        acc2[2] += __builtin_amdgcn_cvt_pk_f32_fp8((int)(a).y, false);           \
        acc2[3] += __builtin_amdgcn_cvt_pk_f32_fp8((int)(a).y, true);            \
    }

__global__ __launch_bounds__(256) void agg1_kernel(const unsigned char* __restrict__ u,
                                                   const int2* __restrict__ bele,
                                                   const int* __restrict__ col,
                                                   const float* __restrict__ dinv,
                                                   const float* __restrict__ bias,
                                                   const float* __restrict__ Wz,
                                                   float2* __restrict__ qz, int n) {
    __shared__ float Wz0s[64];
    __shared__ float Wz1s[64];
    int tid = threadIdx.x;
    if (tid < 64) Wz0s[tid] = Wz[tid * 2];
    else if (tid < 128) Wz1s[tid - 64] = Wz[(tid - 64) * 2 + 1];
    __syncthreads();

    int wid = tid >> 6, lane = tid & 63;
    int node = blockIdx.x * 4 + wid;
    if (node >= n) return;
    int r = lane >> 3, c = lane & 7;   // edge slot, feat group
    unsigned int c8 = (unsigned int)c * 8;

    int2 be = bele[node];
    int beg = be.x, end = be.y;
    floatx2 acc2[4];
#pragma unroll
    for (int j = 0; j < 4; ++j) acc2[j] = (floatx2)(0.f);

    int e = beg + r;
    while (e + 24 < end) {
        unsigned int v0 = ((unsigned int)__builtin_nontemporal_load(&col[e])      << 3) + c8;
        unsigned int v1 = ((unsigned int)__builtin_nontemporal_load(&col[e + 8])  << 3) + c8;
        unsigned int v2 = ((unsigned int)__builtin_nontemporal_load(&col[e + 16]) << 3) + c8;
        unsigned int v3 = ((unsigned int)__builtin_nontemporal_load(&col[e + 24]) << 3) + c8;
        uint2 a0 = *reinterpret_cast<const uint2*>(u + v0);
        uint2 a1 = *reinterpret_cast<const uint2*>(u + v1);
        uint2 a2 = *reinterpret_cast<const uint2*>(u + v2);
        uint2 a3 = *reinterpret_cast<const uint2*>(u + v3);
        ACC8(a0); ACC8(a1); ACC8(a2); ACC8(a3);
        e += 32;
    }
    while (e + 8 < end) {
        unsigned int v0 = ((unsigned int)__builtin_nontemporal_load(&col[e])     << 3) + c8;
        unsigned int v1 = ((unsigned int)__builtin_nontemporal_load(&col[e + 8]) << 3) + c8;
        uint2 a0 = *reinterpret_cast<const uint2*>(u + v0);
        uint2 a1 = *reinterpret_cast<const uint2*>(u + v1);
        ACC8(a0); ACC8(a1);
        e += 16;
    }
    if (e < end) {
        unsigned int v0 = ((unsigned int)__builtin_nontemporal_load(&col[e]) << 3) + c8;
        uint2 a0 = *reinterpret_cast<const uint2*>(u + v0);
        ACC8(a0);
    }
    // reduce across the 8 edge slots (lane bits 3..5)
#pragma unroll
    for (int m = 8; m <= 32; m <<= 1) {
#pragma unroll
        for (int j = 0; j < 4; ++j) {
            acc2[j].x += __shfl_xor(acc2[j].x, m);
            acc2[j].y += __shfl_xor(acc2[j].y, m);
        }
    }
    if (r == 0) {
        unsigned int vs = ((unsigned int)node << 6) + c8;
        uint2 sfr = *reinterpret_cast<const uint2*>(u + vs);
        ACC8(sfr);   // add self row
        float di = dinv[node];
        float4 b0 = *reinterpret_cast<const float4*>(&bias[c * 8]);
        float4 b1 = *reinterpret_cast<const float4*>(&bias[c * 8 + 4]);
        float o[8];
#pragma unroll
        for (int j = 0; j < 4; ++j) {
            o[2 * j]     = di * acc2[j].x;
            o[2 * j + 1] = di * acc2[j].y;
        }
        o[0] += b0.x; o[1] += b0.y; o[2] += b0.z; o[3] += b0.w;
        o[4] += b1.x; o[5] += b1.y; o[6] += b1.z; o[7] += b1.w;
#pragma unroll
        for (int j = 0; j < 8; ++j) o[j] = fmaxf(o[j], 0.f);
        float p0 = 0.f, p1 = 0.f;
#pragma unroll
        for (int j = 0; j < 8; ++j) {
            p0 += o[j] * Wz0s[c * 8 + j];
            p1 += o[j] * Wz1s[c * 8 + j];
        }
#pragma unroll
        for (int m = 1; m <= 4; m <<= 1) {
            p0 += __shfl_xor(p0, m);
            p1 += __shfl_xor(p1, m);
        }
        if (lane == 0) qz[node] = make_float2(p0 * di, p1 * di);
    }
}

// ---------- agg2q: 16 lanes/node x 16 nodes/block, float2 gathers from qz,
// fused segmented pooling into pooled2[g*2+j] ----------
__global__ __launch_bounds__(256) void agg2q_kernel(const float2* __restrict__ qz,
                                                    const int2* __restrict__ bele,
                                                    const int* __restrict__ col,
                                                    const float* __restrict__ dinv,
                                                    float* __restrict__ pooled2,
                                                    const int* __restrict__ batch, int n) {
    __shared__ float2 sh[16];
    __shared__ int sg[16];
    int tid = threadIdx.x;
    int wid = tid >> 6, lane = tid & 63;
    int sub = lane >> 4, slot = lane & 15;
    int li = wid * 4 + sub;                 // 0..15 node slot in block
    int node = blockIdx.x * 16 + li;
    bool valid = node < n;

    float ax = 0.f, ay = 0.f;
    if (valid) {
        int2 be = bele[node];
        const char* qb = (const char*)qz;
        int e = be.x + slot;
        while (e + 16 < be.y) {
            unsigned int o0 = (unsigned int)__builtin_nontemporal_load(&col[e]);
            unsigned int o1 = (unsigned int)__builtin_nontemporal_load(&col[e + 16]);
            float2 v0 = *reinterpret_cast<const float2*>(qb + o0);
            float2 v1 = *reinterpret_cast<const float2*>(qb + o1);
            ax += v0.x + v1.x; ay += v0.y + v1.y;
            e += 32;
        }
        if (e < be.y) {
            unsigned int o0 = (unsigned int)__builtin_nontemporal_load(&col[e]);
            float2 v0 = *reinterpret_cast<const float2*>(qb + o0);
            ax += v0.x; ay += v0.y;
        }
    }
#pragma unroll
    for (int m = 1; m <= 8; m <<= 1) {
        ax += __shfl_xor(ax, m);
        ay += __shfl_xor(ay, m);
    }
    if (slot == 0) {
        if (valid) {
            float2 self = qz[node];
            float di = dinv[node];
            sh[li] = make_float2(di * (ax + self.x), di * (ay + self.y));
            sg[li] = batch[node];
        } else {
            sh[li] = make_float2(0.f, 0.f);
            sg[li] = -1;
        }
    }
    __syncthreads();
    if (tid < 2) {
        float s = 0.f;
        int gp = -1;
        for (int w = 0; w < 16; ++w) {
            int g = sg[w];
            if (g < 0) continue;
            if (g != gp) {
                if (gp >= 0) atomicAdd(&pooled2[gp * 2 + tid], s);
                s = 0.f;
                gp = g;
            }
            s += (tid == 0) ? sh[w].x : sh[w].y;
        }
        if (gp >= 0) atomicAdd(&pooled2[gp * 2 + tid], s);
    }
}

// ---------- head: counts via binary search, z = pooled2/cnt + zc, softmax over graphs ----------
__global__ __launch_bounds__(512) void head_kernel(const float* __restrict__ pooled2,
                                                   const int* __restrict__ batch,
                                                   const float* __restrict__ zc,
                                                   float* __restrict__ out, int N) {
    __shared__ float red[512];
    int tid = threadIdx.x;
    int g = tid;
    auto lb = [&](int key) {
        int l = 0, r = N;
        while (l < r) { int m = (l + r) >> 1; if (batch[m] < key) l = m + 1; else r = m; }
        return l;
    };
    int cnt = lb(g + 1) - lb(g);
    float cn = fmaxf((float)cnt, 1.f);
    float z0 = pooled2[g * 2 + 0] / cn + zc[0];
    float z1 = pooled2[g * 2 + 1] / cn + zc[1];

    red[tid] = z0; __syncthreads();
    for (int s = 256; s > 0; s >>= 1) { if (tid < s) red[tid] = fmaxf(red[tid], red[tid + s]); __syncthreads(); }
    float m0 = red[0]; __syncthreads();
    float e0 = expf(z0 - m0);
    red[tid] = e0; __syncthreads();
    for (int s = 256; s > 0; s >>= 1) { if (tid < s) red[tid] += red[tid + s]; __syncthreads(); }
    float s0 = red[0]; __syncthreads();
    out[g * 2 + 0] = e0 / s0;

    red[tid] = z1; __syncthreads();
    for (int s = 256; s > 0; s >>= 1) { if (tid < s) red[tid] = fmaxf(red[tid], red[tid + s]); __syncthreads(); }
    float m1 = red[0]; __syncthreads();
    float e1 = expf(z1 - m1);
    red[tid] = e1; __syncthreads();
    for (int s = 256; s > 0; s >>= 1) { if (tid < s) red[tid] += red[tid + s]; __syncthreads(); }
    float s1 = red[0]; __syncthreads();
    out[g * 2 + 1] = e1 / s1;
}

// ---------- launch ----------
extern "C" void kernel_launch(void* const* d_in, const int* in_sizes, int n_in,
                              void* d_out, int out_size, void* d_ws, size_t ws_size,
                              hipStream_t stream) {
    const float* x   = (const float*)d_in[0];
    const int*   ei  = (const int*)d_in[1];
    const int*   bat = (const int*)d_in[2];
    const float* W1  = (const float*)d_in[3];
    const float* b1  = (const float*)d_in[4];
    const float* W2  = (const float*)d_in[5];
    const float* b2  = (const float*)d_in[6];
    const float* Wl1 = (const float*)d_in[7];
    const float* bl1 = (const float*)d_in[8];
    const float* Wl2 = (const float*)d_in[9];
    const float* bl2 = (const float*)d_in[10];
    float* out = (float*)d_out;

    const int N = N_NODES, E = N_EDGES;
    const int* src = ei;
    const int* dst = ei + E;

    size_t o = 0;
    auto alloc = [&](size_t bytes) {
        void* p = (char*)d_ws + o;
        o += (bytes + 255) / 256 * 256;
        return p;
    };
    int*           cursor  = (int*)alloc((size_t)NB * 4);
    unsigned int*  pairs   = (unsigned int*)alloc((size_t)NB * SLACK * 4 + 4096);
    int*           col     = (int*)alloc((size_t)NB * SLACK * 4 + 4096);
    int2*          bele    = (int2*)alloc((size_t)N * 8);
    float*         dinv    = (float*)alloc((size_t)N * 4);
    unsigned char* T       = (unsigned char*)alloc((size_t)N * 64);
    float2*        qz      = (float2*)alloc((size_t)N * 8);
    float*         Wz      = (float*)alloc(128 * 4);
    float*         zc      = (float*)alloc(2 * 4);
    float*         pooled2 = (float*)alloc((size_t)N_GRAPHS * 2 * 4);

    // setup: cursors, Wz/zc fold, pooled2 zero (single dispatch)
    setup_kernel<<<1, 256, 0, stream>>>(W2, b2, Wl1, bl1, Wl2, bl2, cursor, Wz, zc, pooled2);

    // CSR build: fused single-pass scatter -> per-bucket fine sort
    scatter3_kernel<<<SBLOCKS, 256, 0, stream>>>(src, dst, cursor, pairs, E);
    bucket_kernel<<<NB, 256, 0, stream>>>(pairs, cursor, col, bele, dinv, N);

    // layer 1: U = fp8(dinv * (x @ W1)) ; qz = dinv * relu(dinv*(sum+self)+b1) @ Wz
    lin_kernel<128><<<N / 32, 256, 0, stream>>>(x, W1, dinv, T);
    agg1_kernel<<<(N + 3) / 4, 256, 0, stream>>>(T, bele, col, dinv, b1, Wz, qz, N);

    // layer 2 collapsed to 2 features + fused pooling (16 lanes/node CSR walk)
    agg2q_kernel<<<(N + 15) / 16, 256, 0, stream>>>(qz, bele, col, dinv, pooled2, bat, N);

    // head: counts + mean + const + softmax over graphs
    head_kernel<<<1, 512, 0, stream>>>(pooled2, bat, zc, out, N);
}

// Round 14
// 214.666 us; speedup vs baseline: 1.7127x; 1.7127x over previous
//
#include <hip/hip_runtime.h>
#include <hip/hip_fp16.h>
#include <math.h>

#define N_NODES 100000
#define N_EDGES 3200000
#define N_GRAPHS 512

#define BSHIFT 7
#define BSPAN 128                      // nodes per bucket
#define NB 782                         // ceil(N_NODES / BSPAN)
#define SLACK 4800                     // bucket capacity (mean 4096 + ~11 sigma)
#define SBLK 4096                      // edges per scatter block
#define SBLOCKS ((N_EDGES + SBLK - 1) / SBLK)   // 782

typedef float floatx2 __attribute__((ext_vector_type(2)));

// ---------- setup: cursors + Wz fold + pooled2 zero (one dispatch) ----------
__global__ __launch_bounds__(256) void setup_kernel(const float* __restrict__ W2,
                                                    const float* __restrict__ b2,
                                                    const float* __restrict__ Wl1,
                                                    const float* __restrict__ bl1,
                                                    const float* __restrict__ Wl2,
                                                    const float* __restrict__ bl2,
                                                    int* __restrict__ cursor,
                                                    float* __restrict__ Wz,
                                                    float* __restrict__ zc,
                                                    float* __restrict__ pooled2) {
    __shared__ float Weff[64 * 2];
    int tid = threadIdx.x;
    for (int i = tid; i < NB; i += 256) cursor[i] = i * SLACK;
    for (int i = tid; i < N_GRAPHS * 2; i += 256) pooled2[i] = 0.f;
    if (tid < 128) {
        int c = tid >> 1, j = tid & 1;
        float s = 0.f;
        for (int k = 0; k < 32; ++k) s += Wl1[c * 32 + k] * Wl2[k * 2 + j];
        Weff[c * 2 + j] = s;
    }
    __syncthreads();
    if (tid < 128) {
        int i = tid >> 1, j = tid & 1;
        float s = 0.f;
        for (int c = 0; c < 64; ++c) s += W2[i * 64 + c] * Weff[c * 2 + j];
        Wz[i * 2 + j] = s;
    }
    if (tid < 2) {
        float s = bl2[tid];
        for (int k = 0; k < 32; ++k) s += bl1[k] * Wl2[k * 2 + tid];
        for (int c = 0; c < 64; ++c) s += b2[c] * Weff[c * 2 + tid];
        zc[tid] = s;
    }
}

// ---------- scatter3: register-staged single-pass histogram+reserve+scatter ----------
__global__ __launch_bounds__(256) void scatter3_kernel(const int* __restrict__ src,
                                                       const int* __restrict__ dst,
                                                       int* __restrict__ cursor,
                                                       unsigned int* __restrict__ pairs, int E) {
    __shared__ int hcnt[NB];
    __shared__ int hbase[NB];
    int tid = threadIdx.x;
    for (int b = tid; b < NB; b += 256) hcnt[b] = 0;
    __syncthreads();
    int base = blockIdx.x * SBLK;
    int end = min(E, base + SBLK);
    int4 dv[4], sv[4];
    int rk[16];
    bool ok[4];
#pragma unroll
    for (int k = 0; k < 4; ++k) {
        int e = base + tid * 4 + k * 1024;
        ok[k] = (e < end);                      // whole int4 in or out
        if (ok[k]) {
            dv[k] = *reinterpret_cast<const int4*>(&dst[e]);
            sv[k] = *reinterpret_cast<const int4*>(&src[e]);
        }
    }
#pragma unroll
    for (int k = 0; k < 4; ++k) {
        if (ok[k]) {
            rk[4 * k + 0] = atomicAdd(&hcnt[dv[k].x >> BSHIFT], 1);
            rk[4 * k + 1] = atomicAdd(&hcnt[dv[k].y >> BSHIFT], 1);
            rk[4 * k + 2] = atomicAdd(&hcnt[dv[k].z >> BSHIFT], 1);
            rk[4 * k + 3] = atomicAdd(&hcnt[dv[k].w >> BSHIFT], 1);
        }
    }
    __syncthreads();
    for (int b = tid; b < NB; b += 256) {
        int c = hcnt[b];
        if (c) hbase[b] = atomicAdd(&cursor[b], c);
    }
    __syncthreads();
#pragma unroll
    for (int k = 0; k < 4; ++k) {
        if (ok[k]) {
            pairs[hbase[dv[k].x >> BSHIFT] + rk[4 * k + 0]] =
                ((unsigned int)sv[k].x << BSHIFT) | (unsigned int)(dv[k].x & (BSPAN - 1));
            pairs[hbase[dv[k].y >> BSHIFT] + rk[4 * k + 1]] =
                ((unsigned int)sv[k].y << BSHIFT) | (unsigned int)(dv[k].y & (BSPAN - 1));
            pairs[hbase[dv[k].z >> BSHIFT] + rk[4 * k + 2]] =
                ((unsigned int)sv[k].z << BSHIFT) | (unsigned int)(dv[k].z & (BSPAN - 1));
            pairs[hbase[dv[k].w >> BSHIFT] + rk[4 * k + 3]] =
                ((unsigned int)sv[k].w << BSHIFT) | (unsigned int)(dv[k].w & (BSPAN - 1));
        }
    }
}

// ---------- bucket: per-bucket fine sort -> col (src<<3), bele(beg,end), dinv ----------
__global__ __launch_bounds__(256) void bucket_kernel(const unsigned int* __restrict__ pairs,
                                                     const int* __restrict__ cursor,
                                                     int* __restrict__ col,
                                                     int2* __restrict__ bele,
                                                     float* __restrict__ dinv, int N) {
    __shared__ int ncnt[BSPAN];
    __shared__ int nbase[BSPAN];
    __shared__ int a[BSPAN];
    int b = blockIdx.x, tid = threadIdx.x;
    int base = b * SLACK;
    int cntb = cursor[b] - base;
    int n0 = b << BSHIFT;
    int nn = min(BSPAN, N - n0);
    if (tid < BSPAN) ncnt[tid] = 0;
    __syncthreads();
    for (int i = tid; i < cntb; i += 256)
        atomicAdd(&ncnt[pairs[base + i] & (BSPAN - 1)], 1);
    __syncthreads();
    if (tid < BSPAN) a[tid] = ncnt[tid];
    __syncthreads();
    for (int st = 1; st < BSPAN; st <<= 1) {
        int t = (tid < BSPAN && tid >= st) ? a[tid - st] : 0;
        __syncthreads();
        if (tid < BSPAN) a[tid] += t;
        __syncthreads();
    }
    if (tid < BSPAN) {
        int v = ncnt[tid];
        int excl = a[tid] - v;
        nbase[tid] = excl;
        if (tid < nn) {
            int beg = base + excl;
            bele[n0 + tid] = make_int2(beg, beg + v);
            dinv[n0 + tid] = rsqrtf((float)(v + 1));   // +1 self loop
        }
        ncnt[tid] = 0;   // reuse as cursor
    }
    __syncthreads();
    for (int i = tid; i < cntb; i += 256) {
        unsigned int p = pairs[base + i];
        int dl = p & (BSPAN - 1);
        int pos = base + nbase[dl] + atomicAdd(&ncnt[dl], 1);
        col[pos] = (int)(p >> BSHIFT) << 3;   // byte offset into qz (float2 rows)
    }
}

// ---------- dense linear: U[n,64] = fp8(dinv[n] * (X[n,K] @ W[K,64])) ----------
template <int K>
__global__ __launch_bounds__(256) void lin_kernel(const float* __restrict__ X,
                                                  const float* __restrict__ W,
                                                  const float* __restrict__ rs,
                                                  unsigned char* __restrict__ U) {
    __shared__ float Ws[K * 64];
    __shared__ float Xs[32 * K];
    int tid = threadIdx.x;
    for (int i = tid * 4; i < K * 64; i += 256 * 4)
        *reinterpret_cast<float4*>(&Ws[i]) = *reinterpret_cast<const float4*>(&W[i]);
    int row0 = blockIdx.x * 32;
    const float* Xbase = X + (size_t)row0 * K;
    for (int i = tid * 4; i < 32 * K; i += 256 * 4)
        *reinterpret_cast<float4*>(&Xs[i]) = *reinterpret_cast<const float4*>(&Xbase[i]);
    __syncthreads();

    int wid = tid >> 6, lane = tid & 63;
    int rbase = wid * 8;
    float acc[8];
#pragma unroll
    for (int r = 0; r < 8; ++r) acc[r] = 0.f;

    for (int k4 = 0; k4 < K / 4; ++k4) {
        float w0 = Ws[(k4 * 4 + 0) * 64 + lane];
        float w1 = Ws[(k4 * 4 + 1) * 64 + lane];
        float w2 = Ws[(k4 * 4 + 2) * 64 + lane];
        float w3 = Ws[(k4 * 4 + 3) * 64 + lane];
#pragma unroll
        for (int r = 0; r < 8; ++r) {
            float4 xv = *reinterpret_cast<const float4*>(&Xs[(rbase + r) * K + k4 * 4]);
            acc[r] += xv.x * w0 + xv.y * w1 + xv.z * w2 + xv.w * w3;
        }
    }
#pragma unroll
    for (int r = 0; r < 8; ++r) {
        int row = row0 + rbase + r;
        float v = acc[r] * rs[row];
        int pk = __builtin_amdgcn_cvt_pk_fp8_f32(v, v, 0, false);
        U[(size_t)row * 64 + lane] = (unsigned char)(pk & 0xff);
    }
}

// ---------- agg1: wave = node, 8 lanes/edge x 8 strided edge slots, fp8 gathers,
// packed f32 accum. Epilogue (r==0): relu+bias, @Wz fold, write qz. ----------
#define ACC8(a)                                                                  \
    {                                                                            \
        acc2[0] += __builtin_amdgcn_cvt_pk_f32_fp8((int)(a).x, false);           \
        acc2[1] += __builtin_amdgcn_cvt_pk_f32_fp8((int)(a).x, true);            \
        acc2[2] += __builtin_amdgcn_cvt_pk_f32_fp8((int)(a).y, false);           \
        acc2[3] += __builtin_amdgcn_cvt_pk_f32_fp8((int)(a).y, true);            \
    }

__global__ __launch_bounds__(256) void agg1_kernel(const unsigned char* __restrict__ u,
                                                   const int2* __restrict__ bele,
                                                   const int* __restrict__ col,
                                                   const float* __restrict__ dinv,
                                                   const float* __restrict__ bias,
                                                   const float* __restrict__ Wz,
                                                   float2* __restrict__ qz, int n) {
    __shared__ float Wz0s[64];
    __shared__ float Wz1s[64];
    int tid = threadIdx.x;
    if (tid < 64) Wz0s[tid] = Wz[tid * 2];
    else if (tid < 128) Wz1s[tid - 64] = Wz[(tid - 64) * 2 + 1];
    __syncthreads();

    int wid = tid >> 6, lane = tid & 63;
    int node = blockIdx.x * 4 + wid;
    if (node >= n) return;
    int r = lane >> 3, c = lane & 7;   // edge slot, feat group
    unsigned int c8 = (unsigned int)c * 8;

    int2 be = bele[node];
    int beg = be.x, end = be.y;
    floatx2 acc2[4];
#pragma unroll
    for (int j = 0; j < 4; ++j) acc2[j] = (floatx2)(0.f);

    int e = beg + r;
    while (e + 24 < end) {
        unsigned int v0 = ((unsigned int)col[e]      << 3) + c8;
        unsigned int v1 = ((unsigned int)col[e + 8]  << 3) + c8;
        unsigned int v2 = ((unsigned int)col[e + 16] << 3) + c8;
        unsigned int v3 = ((unsigned int)col[e + 24] << 3) + c8;
        uint2 a0 = *reinterpret_cast<const uint2*>(u + v0);
        uint2 a1 = *reinterpret_cast<const uint2*>(u + v1);
        uint2 a2 = *reinterpret_cast<const uint2*>(u + v2);
        uint2 a3 = *reinterpret_cast<const uint2*>(u + v3);
        ACC8(a0); ACC8(a1); ACC8(a2); ACC8(a3);
        e += 32;
    }
    while (e + 8 < end) {
        unsigned int v0 = ((unsigned int)col[e]     << 3) + c8;
        unsigned int v1 = ((unsigned int)col[e + 8] << 3) + c8;
        uint2 a0 = *reinterpret_cast<const uint2*>(u + v0);
        uint2 a1 = *reinterpret_cast<const uint2*>(u + v1);
        ACC8(a0); ACC8(a1);
        e += 16;
    }
    if (e < end) {
        unsigned int v0 = ((unsigned int)col[e] << 3) + c8;
        uint2 a0 = *reinterpret_cast<const uint2*>(u + v0);
        ACC8(a0);
    }
    // reduce across the 8 edge slots (lane bits 3..5)
#pragma unroll
    for (int m = 8; m <= 32; m <<= 1) {
#pragma unroll
        for (int j = 0; j < 4; ++j) {
            acc2[j].x += __shfl_xor(acc2[j].x, m);
            acc2[j].y += __shfl_xor(acc2[j].y, m);
        }
    }
    if (r == 0) {
        unsigned int vs = ((unsigned int)node << 6) + c8;
        uint2 sfr = *reinterpret_cast<const uint2*>(u + vs);
        ACC8(sfr);   // add self row
        float di = dinv[node];
        float4 b0 = *reinterpret_cast<const float4*>(&bias[c * 8]);
        float4 b1 = *reinterpret_cast<const float4*>(&bias[c * 8 + 4]);
        float o[8];
#pragma unroll
        for (int j = 0; j < 4; ++j) {
            o[2 * j]     = di * acc2[j].x;
            o[2 * j + 1] = di * acc2[j].y;
        }
        o[0] += b0.x; o[1] += b0.y; o[2] += b0.z; o[3] += b0.w;
        o[4] += b1.x; o[5] += b1.y; o[6] += b1.z; o[7] += b1.w;
#pragma unroll
        for (int j = 0; j < 8; ++j) o[j] = fmaxf(o[j], 0.f);
        float p0 = 0.f, p1 = 0.f;
#pragma unroll
        for (int j = 0; j < 8; ++j) {
            p0 += o[j] * Wz0s[c * 8 + j];
            p1 += o[j] * Wz1s[c * 8 + j];
        }
#pragma unroll
        for (int m = 1; m <= 4; m <<= 1) {
            p0 += __shfl_xor(p0, m);
            p1 += __shfl_xor(p1, m);
        }
        if (lane == 0) qz[node] = make_float2(p0 * di, p1 * di);
    }
}

// ---------- agg2q: 16 lanes/node x 16 nodes/block, float2 gathers from qz,
// fused segmented pooling into pooled2[g*2+j] ----------
__global__ __launch_bounds__(256) void agg2q_kernel(const float2* __restrict__ qz,
                                                    const int2* __restrict__ bele,
                                                    const int* __restrict__ col,
                                                    const float* __restrict__ dinv,
                                                    float* __restrict__ pooled2,
                                                    const int* __restrict__ batch, int n) {
    __shared__ float2 sh[16];
    __shared__ int sg[16];
    int tid = threadIdx.x;
    int wid = tid >> 6, lane = tid & 63;
    int sub = lane >> 4, slot = lane & 15;
    int li = wid * 4 + sub;                 // 0..15 node slot in block
    int node = blockIdx.x * 16 + li;
    bool valid = node < n;

    float ax = 0.f, ay = 0.f;
    if (valid) {
        int2 be = bele[node];
        const char* qb = (const char*)qz;
        int e = be.x + slot;
        while (e + 16 < be.y) {
            float2 v0 = *reinterpret_cast<const float2*>(qb + (unsigned int)col[e]);
            float2 v1 = *reinterpret_cast<const float2*>(qb + (unsigned int)col[e + 16]);
            ax += v0.x + v1.x; ay += v0.y + v1.y;
            e += 32;
        }
        if (e < be.y) {
            float2 v0 = *reinterpret_cast<const float2*>(qb + (unsigned int)col[e]);
            ax += v0.x; ay += v0.y;
        }
    }
#pragma unroll
    for (int m = 1; m <= 8; m <<= 1) {
        ax += __shfl_xor(ax, m);
        ay += __shfl_xor(ay, m);
    }
    if (slot == 0) {
        if (valid) {
            float2 self = qz[node];
            float di = dinv[node];
            sh[li] = make_float2(di * (ax + self.x), di * (ay + self.y));
            sg[li] = batch[node];
        } else {
            sh[li] = make_float2(0.f, 0.f);
            sg[li] = -1;
        }
    }
    __syncthreads();
    if (tid < 2) {
        float s = 0.f;
        int gp = -1;
        for (int w = 0; w < 16; ++w) {
            int g = sg[w];
            if (g < 0) continue;
            if (g != gp) {
                if (gp >= 0) atomicAdd(&pooled2[gp * 2 + tid], s);
                s = 0.f;
                gp = g;
            }
            s += (tid == 0) ? sh[w].x : sh[w].y;
        }
        if (gp >= 0) atomicAdd(&pooled2[gp * 2 + tid], s);
    }
}

// ---------- head: counts via binary search, z = pooled2/cnt + zc, softmax over graphs ----------
__global__ __launch_bounds__(512) void head_kernel(const float* __restrict__ pooled2,
                                                   const int* __restrict__ batch,
                                                   const float* __restrict__ zc,
                                                   float* __restrict__ out, int N) {
    __shared__ float red[512];
    int tid = threadIdx.x;
    int g = tid;
    auto lb = [&](int key) {
        int l = 0, r = N;
        while (l < r) { int m = (l + r) >> 1; if (batch[m] < key) l = m + 1; else r = m; }
        return l;
    };
    int cnt = lb(g + 1) - lb(g);
    float cn = fmaxf((float)cnt, 1.f);
    float z0 = pooled2[g * 2 + 0] / cn + zc[0];
    float z1 = pooled2[g * 2 + 1] / cn + zc[1];

    red[tid] = z0; __syncthreads();
    for (int s = 256; s > 0; s >>= 1) { if (tid < s) red[tid] = fmaxf(red[tid], red[tid + s]); __syncthreads(); }
    float m0 = red[0]; __syncthreads();
    float e0 = expf(z0 - m0);
    red[tid] = e0; __syncthreads();
    for (int s = 256; s > 0; s >>= 1) { if (tid < s) red[tid] += red[tid + s]; __syncthreads(); }
    float s0 = red[0]; __syncthreads();
    out[g * 2 + 0] = e0 / s0;

    red[tid] = z1; __syncthreads();
    for (int s = 256; s > 0; s >>= 1) { if (tid < s) red[tid] = fmaxf(red[tid], red[tid + s]); __syncthreads(); }
    float m1 = red[0]; __syncthreads();
    float e1 = expf(z1 - m1);
    red[tid] = e1; __syncthreads();
    for (int s = 256; s > 0; s >>= 1) { if (tid < s) red[tid] += red[tid + s]; __syncthreads(); }
    float s1 = red[0]; __syncthreads();
    out[g * 2 + 1] = e1 / s1;
}

// ---------- launch ----------
extern "C" void kernel_launch(void* const* d_in, const int* in_sizes, int n_in,
                              void* d_out, int out_size, void* d_ws, size_t ws_size,
                              hipStream_t stream) {
    const float* x   = (const float*)d_in[0];
    const int*   ei  = (const int*)d_in[1];
    const int*   bat = (const int*)d_in[2];
    const float* W1  = (const float*)d_in[3];
    const float* b1  = (const float*)d_in[4];
    const float* W2  = (const float*)d_in[5];
    const float* b2  = (const float*)d_in[6];
    const float* Wl1 = (const float*)d_in[7];
    const float* bl1 = (const float*)d_in[8];
    const float* Wl2 = (const float*)d_in[9];
    const float* bl2 = (const float*)d_in[10];
    float* out = (float*)d_out;

    const int N = N_NODES, E = N_EDGES;
    const int* src = ei;
    const int* dst = ei + E;

    size_t o = 0;
    auto alloc = [&](size_t bytes) {
        void* p = (char*)d_ws + o;
        o += (bytes + 255) / 256 * 256;
        return p;
    };
    int*           cursor  = (int*)alloc((size_t)NB * 4);
    unsigned int*  pairs   = (unsigned int*)alloc((size_t)NB * SLACK * 4 + 4096);
    int*           col     = (int*)alloc((size_t)NB * SLACK * 4 + 4096);
    int2*          bele    = (int2*)alloc((size_t)N * 8);
    float*         dinv    = (float*)alloc((size_t)N * 4);
    unsigned char* T       = (unsigned char*)alloc((size_t)N * 64);
    float2*        qz      = (float2*)alloc((size_t)N * 8);
    float*         Wz      = (float*)alloc(128 * 4);
    float*         zc      = (float*)alloc(2 * 4);
    float*         pooled2 = (float*)alloc((size_t)N_GRAPHS * 2 * 4);

    // setup: cursors, Wz/zc fold, pooled2 zero (single dispatch)
    setup_kernel<<<1, 256, 0, stream>>>(W2, b2, Wl1, bl1, Wl2, bl2, cursor, Wz, zc, pooled2);

    // CSR build: fused single-pass scatter -> per-bucket fine sort
    scatter3_kernel<<<SBLOCKS, 256, 0, stream>>>(src, dst, cursor, pairs, E);
    bucket_kernel<<<NB, 256, 0, stream>>>(pairs, cursor, col, bele, dinv, N);

    // layer 1: U = fp8(dinv * (x @ W1)) ; qz = dinv * relu(dinv*(sum+self)+b1) @ Wz
    lin_kernel<128><<<N / 32, 256, 0, stream>>>(x, W1, dinv, T);
    agg1_kernel<<<(N + 3) / 4, 256, 0, stream>>>(T, bele, col, dinv, b1, Wz, qz, N);

    // layer 2 collapsed to 2 features + fused pooling (16 lanes/node CSR walk)
    agg2q_kernel<<<(N + 15) / 16, 256, 0, stream>>>(qz, bele, col, dinv, pooled2, bat, N);

    // head: counts + mean + const + softmax over graphs
    head_kernel<<<1, 512, 0, stream>>>(pooled2, bat, zc, out, N);
}

// Round 15
// 213.055 us; speedup vs baseline: 1.7257x; 1.0076x over previous
//
#include <hip/hip_runtime.h>
#include <hip/hip_fp16.h>
#include <math.h>

#define N_NODES 100000
#define N_EDGES 3200000
#define N_GRAPHS 512

#define BSHIFT 7
#define BSPAN 128                      // nodes per bucket
#define NB 782                         // ceil(N_NODES / BSPAN)
#define SLACK 4800                     // bucket capacity (mean 4096 + ~11 sigma)
#define SBLK 4096                      // edges per scatter block
#define SBLOCKS ((N_EDGES + SBLK - 1) / SBLK)   // 782
#define BITEMS ((SLACK + 255) / 256)            // 19 reg-stash items per thread

typedef float floatx2 __attribute__((ext_vector_type(2)));

// ---------- setup: cursors + Wz fold + pooled2 zero (one dispatch) ----------
__global__ __launch_bounds__(256) void setup_kernel(const float* __restrict__ W2,
                                                    const float* __restrict__ b2,
                                                    const float* __restrict__ Wl1,
                                                    const float* __restrict__ bl1,
                                                    const float* __restrict__ Wl2,
                                                    const float* __restrict__ bl2,
                                                    int* __restrict__ cursor,
                                                    float* __restrict__ Wz,
                                                    float* __restrict__ zc,
                                                    float* __restrict__ pooled2) {
    __shared__ float Weff[64 * 2];
    int tid = threadIdx.x;
    for (int i = tid; i < NB; i += 256) cursor[i] = i * SLACK;
    for (int i = tid; i < N_GRAPHS * 2; i += 256) pooled2[i] = 0.f;
    if (tid < 128) {
        int c = tid >> 1, j = tid & 1;
        float s = 0.f;
        for (int k = 0; k < 32; ++k) s += Wl1[c * 32 + k] * Wl2[k * 2 + j];
        Weff[c * 2 + j] = s;
    }
    __syncthreads();
    if (tid < 128) {
        int i = tid >> 1, j = tid & 1;
        float s = 0.f;
        for (int c = 0; c < 64; ++c) s += W2[i * 64 + c] * Weff[c * 2 + j];
        Wz[i * 2 + j] = s;
    }
    if (tid < 2) {
        float s = bl2[tid];
        for (int k = 0; k < 32; ++k) s += bl1[k] * Wl2[k * 2 + tid];
        for (int c = 0; c < 64; ++c) s += b2[c] * Weff[c * 2 + tid];
        zc[tid] = s;
    }
}

// ---------- scatter3: register-staged single-pass histogram+reserve+scatter ----------
__global__ __launch_bounds__(256) void scatter3_kernel(const int* __restrict__ src,
                                                       const int* __restrict__ dst,
                                                       int* __restrict__ cursor,
                                                       unsigned int* __restrict__ pairs, int E) {
    __shared__ int hcnt[NB];
    __shared__ int hbase[NB];
    int tid = threadIdx.x;
    for (int b = tid; b < NB; b += 256) hcnt[b] = 0;
    __syncthreads();
    int base = blockIdx.x * SBLK;
    int end = min(E, base + SBLK);
    int4 dv[4], sv[4];
    int rk[16];
    bool ok[4];
#pragma unroll
    for (int k = 0; k < 4; ++k) {
        int e = base + tid * 4 + k * 1024;
        ok[k] = (e < end);                      // whole int4 in or out
        if (ok[k]) {
            dv[k] = *reinterpret_cast<const int4*>(&dst[e]);
            sv[k] = *reinterpret_cast<const int4*>(&src[e]);
        }
    }
#pragma unroll
    for (int k = 0; k < 4; ++k) {
        if (ok[k]) {
            rk[4 * k + 0] = atomicAdd(&hcnt[dv[k].x >> BSHIFT], 1);
            rk[4 * k + 1] = atomicAdd(&hcnt[dv[k].y >> BSHIFT], 1);
            rk[4 * k + 2] = atomicAdd(&hcnt[dv[k].z >> BSHIFT], 1);
            rk[4 * k + 3] = atomicAdd(&hcnt[dv[k].w >> BSHIFT], 1);
        }
    }
    __syncthreads();
    for (int b = tid; b < NB; b += 256) {
        int c = hcnt[b];
        if (c) hbase[b] = atomicAdd(&cursor[b], c);
    }
    __syncthreads();
#pragma unroll
    for (int k = 0; k < 4; ++k) {
        if (ok[k]) {
            pairs[hbase[dv[k].x >> BSHIFT] + rk[4 * k + 0]] =
                ((unsigned int)sv[k].x << BSHIFT) | (unsigned int)(dv[k].x & (BSPAN - 1));
            pairs[hbase[dv[k].y >> BSHIFT] + rk[4 * k + 1]] =
                ((unsigned int)sv[k].y << BSHIFT) | (unsigned int)(dv[k].y & (BSPAN - 1));
            pairs[hbase[dv[k].z >> BSHIFT] + rk[4 * k + 2]] =
                ((unsigned int)sv[k].z << BSHIFT) | (unsigned int)(dv[k].z & (BSPAN - 1));
            pairs[hbase[dv[k].w >> BSHIFT] + rk[4 * k + 3]] =
                ((unsigned int)sv[k].w << BSHIFT) | (unsigned int)(dv[k].w & (BSPAN - 1));
        }
    }
}

// ---------- bucket: single-pass reg-stash fine sort -> col (src<<3), bele, dinv ----------
__global__ __launch_bounds__(256) void bucket_kernel(const unsigned int* __restrict__ pairs,
                                                     const int* __restrict__ cursor,
                                                     int* __restrict__ col,
                                                     int2* __restrict__ bele,
                                                     float* __restrict__ dinv, int N) {
    __shared__ int ncnt[BSPAN];
    __shared__ int nbase[BSPAN];
    __shared__ int a[BSPAN];
    int b = blockIdx.x, tid = threadIdx.x;
    int base = b * SLACK;
    int cntb = cursor[b] - base;
    int n0 = b << BSHIFT;
    int nn = min(BSPAN, N - n0);
    if (tid < BSPAN) ncnt[tid] = 0;
    __syncthreads();
    unsigned int stash[BITEMS];
#pragma unroll
    for (int k = 0; k < BITEMS; ++k) {
        int i = tid + k * 256;
        if (i < cntb) {
            unsigned int p = pairs[base + i];
            stash[k] = p;
            atomicAdd(&ncnt[p & (BSPAN - 1)], 1);
        }
    }
    __syncthreads();
    if (tid < BSPAN) a[tid] = ncnt[tid];
    __syncthreads();
    for (int st = 1; st < BSPAN; st <<= 1) {
        int t = (tid < BSPAN && tid >= st) ? a[tid - st] : 0;
        __syncthreads();
        if (tid < BSPAN) a[tid] += t;
        __syncthreads();
    }
    if (tid < BSPAN) {
        int v = ncnt[tid];
        int excl = a[tid] - v;
        nbase[tid] = excl;
        if (tid < nn) {
            int beg = base + excl;
            bele[n0 + tid] = make_int2(beg, beg + v);
            dinv[n0 + tid] = rsqrtf((float)(v + 1));   // +1 self loop
        }
        ncnt[tid] = 0;   // reuse as cursor
    }
    __syncthreads();
#pragma unroll
    for (int k = 0; k < BITEMS; ++k) {
        int i = tid + k * 256;
        if (i < cntb) {
            unsigned int p = stash[k];
            int dl = p & (BSPAN - 1);
            int pos = base + nbase[dl] + atomicAdd(&ncnt[dl], 1);
            col[pos] = (int)(p >> BSHIFT) << 3;   // byte offset into qz (float2 rows)
        }
    }
}

// ---------- dense linear: U[n,64] = fp8(dinv[n] * (X[n,K] @ W[K,64])) ----------
template <int K>
__global__ __launch_bounds__(256) void lin_kernel(const float* __restrict__ X,
                                                  const float* __restrict__ W,
                                                  const float* __restrict__ rs,
                                                  unsigned char* __restrict__ U) {
    __shared__ float Ws[K * 64];
    __shared__ float Xs[32 * K];
    int tid = threadIdx.x;
    for (int i = tid * 4; i < K * 64; i += 256 * 4)
        *reinterpret_cast<float4*>(&Ws[i]) = *reinterpret_cast<const float4*>(&W[i]);
    int row0 = blockIdx.x * 32;
    const float* Xbase = X + (size_t)row0 * K;
    for (int i = tid * 4; i < 32 * K; i += 256 * 4)
        *reinterpret_cast<float4*>(&Xs[i]) = *reinterpret_cast<const float4*>(&Xbase[i]);
    __syncthreads();

    int wid = tid >> 6, lane = tid & 63;
    int rbase = wid * 8;
    float acc[8];
#pragma unroll
    for (int r = 0; r < 8; ++r) acc[r] = 0.f;

    for (int k4 = 0; k4 < K / 4; ++k4) {
        float w0 = Ws[(k4 * 4 + 0) * 64 + lane];
        float w1 = Ws[(k4 * 4 + 1) * 64 + lane];
        float w2 = Ws[(k4 * 4 + 2) * 64 + lane];
        float w3 = Ws[(k4 * 4 + 3) * 64 + lane];
#pragma unroll
        for (int r = 0; r < 8; ++r) {
            float4 xv = *reinterpret_cast<const float4*>(&Xs[(rbase + r) * K + k4 * 4]);
            acc[r] += xv.x * w0 + xv.y * w1 + xv.z * w2 + xv.w * w3;
        }
    }
#pragma unroll
    for (int r = 0; r < 8; ++r) {
        int row = row0 + rbase + r;
        float v = acc[r] * rs[row];
        int pk = __builtin_amdgcn_cvt_pk_fp8_f32(v, v, 0, false);
        U[(size_t)row * 64 + lane] = (unsigned char)(pk & 0xff);
    }
}

// ---------- agg1: wave = node, 8 lanes/edge x 8 strided edge slots, fp8 gathers,
// packed f32 accum. Epilogue (r==0): relu+bias, @Wz fold, write qz. ----------
#define ACC8(a)                                                                  \
    {                                                                            \
        acc2[0] += __builtin_amdgcn_cvt_pk_f32_fp8((int)(a).x, false);           \
        acc2[1] += __builtin_amdgcn_cvt_pk_f32_fp8((int)(a).x, true);            \
        acc2[2] += __builtin_amdgcn_cvt_pk_f32_fp8((int)(a).y, false);           \
        acc2[3] += __builtin_amdgcn_cvt_pk_f32_fp8((int)(a).y, true);            \
    }

__global__ __launch_bounds__(256) void agg1_kernel(const unsigned char* __restrict__ u,
                                                   const int2* __restrict__ bele,
                                                   const int* __restrict__ col,
                                                   const float* __restrict__ dinv,
                                                   const float* __restrict__ bias,
                                                   const float* __restrict__ Wz,
                                                   float2* __restrict__ qz, int n) {
    __shared__ float Wz0s[64];
    __shared__ float Wz1s[64];
    int tid = threadIdx.x;
    if (tid < 64) Wz0s[tid] = Wz[tid * 2];
    else if (tid < 128) Wz1s[tid - 64] = Wz[(tid - 64) * 2 + 1];
    __syncthreads();

    int wid = tid >> 6, lane = tid & 63;
    int node = blockIdx.x * 4 + wid;
    if (node >= n) return;
    int r = lane >> 3, c = lane & 7;   // edge slot, feat group
    unsigned int c8 = (unsigned int)c * 8;

    int2 be = bele[node];
    int beg = be.x, end = be.y;
    floatx2 acc2[4];
#pragma unroll
    for (int j = 0; j < 4; ++j) acc2[j] = (floatx2)(0.f);

    int e = beg + r;
    while (e + 24 < end) {
        unsigned int v0 = ((unsigned int)col[e]      << 3) + c8;
        unsigned int v1 = ((unsigned int)col[e + 8]  << 3) + c8;
        unsigned int v2 = ((unsigned int)col[e + 16] << 3) + c8;
        unsigned int v3 = ((unsigned int)col[e + 24] << 3) + c8;
        uint2 a0 = *reinterpret_cast<const uint2*>(u + v0);
        uint2 a1 = *reinterpret_cast<const uint2*>(u + v1);
        uint2 a2 = *reinterpret_cast<const uint2*>(u + v2);
        uint2 a3 = *reinterpret_cast<const uint2*>(u + v3);
        ACC8(a0); ACC8(a1); ACC8(a2); ACC8(a3);
        e += 32;
    }
    while (e + 8 < end) {
        unsigned int v0 = ((unsigned int)col[e]     << 3) + c8;
        unsigned int v1 = ((unsigned int)col[e + 8] << 3) + c8;
        uint2 a0 = *reinterpret_cast<const uint2*>(u + v0);
        uint2 a1 = *reinterpret_cast<const uint2*>(u + v1);
        ACC8(a0); ACC8(a1);
        e += 16;
    }
    if (e < end) {
        unsigned int v0 = ((unsigned int)col[e] << 3) + c8;
        uint2 a0 = *reinterpret_cast<const uint2*>(u + v0);
        ACC8(a0);
    }
    // reduce across the 8 edge slots (lane bits 3..5)
#pragma unroll
    for (int m = 8; m <= 32; m <<= 1) {
#pragma unroll
        for (int j = 0; j < 4; ++j) {
            acc2[j].x += __shfl_xor(acc2[j].x, m);
            acc2[j].y += __shfl_xor(acc2[j].y, m);
        }
    }
    if (r == 0) {
        unsigned int vs = ((unsigned int)node << 6) + c8;
        uint2 sfr = *reinterpret_cast<const uint2*>(u + vs);
        ACC8(sfr);   // add self row
        float di = dinv[node];
        float4 b0 = *reinterpret_cast<const float4*>(&bias[c * 8]);
        float4 b1 = *reinterpret_cast<const float4*>(&bias[c * 8 + 4]);
        float o[8];
#pragma unroll
        for (int j = 0; j < 4; ++j) {
            o[2 * j]     = di * acc2[j].x;
            o[2 * j + 1] = di * acc2[j].y;
        }
        o[0] += b0.x; o[1] += b0.y; o[2] += b0.z; o[3] += b0.w;
        o[4] += b1.x; o[5] += b1.y; o[6] += b1.z; o[7] += b1.w;
#pragma unroll
        for (int j = 0; j < 8; ++j) o[j] = fmaxf(o[j], 0.f);
        float p0 = 0.f, p1 = 0.f;
#pragma unroll
        for (int j = 0; j < 8; ++j) {
            p0 += o[j] * Wz0s[c * 8 + j];
            p1 += o[j] * Wz1s[c * 8 + j];
        }
#pragma unroll
        for (int m = 1; m <= 4; m <<= 1) {
            p0 += __shfl_xor(p0, m);
            p1 += __shfl_xor(p1, m);
        }
        if (lane == 0) qz[node] = make_float2(p0 * di, p1 * di);
    }
}

// ---------- agg2q: 16 lanes/node x 16 nodes/block, float2 gathers from qz,
// fused segmented pooling into pooled2[g*2+j] ----------
__global__ __launch_bounds__(256) void agg2q_kernel(const float2* __restrict__ qz,
                                                    const int2* __restrict__ bele,
                                                    const int* __restrict__ col,
                                                    const float* __restrict__ dinv,
                                                    float* __restrict__ pooled2,
                                                    const int* __restrict__ batch, int n) {
    __shared__ float2 sh[16];
    __shared__ int sg[16];
    int tid = threadIdx.x;
    int wid = tid >> 6, lane = tid & 63;
    int sub = lane >> 4, slot = lane & 15;
    int li = wid * 4 + sub;                 // 0..15 node slot in block
    int node = blockIdx.x * 16 + li;
    bool valid = node < n;

    float ax = 0.f, ay = 0.f;
    if (valid) {
        int2 be = bele[node];
        const char* qb = (const char*)qz;
        int e = be.x + slot;
        while (e + 16 < be.y) {
            float2 v0 = *reinterpret_cast<const float2*>(qb + (unsigned int)col[e]);
            float2 v1 = *reinterpret_cast<const float2*>(qb + (unsigned int)col[e + 16]);
            ax += v0.x + v1.x; ay += v0.y + v1.y;
            e += 32;
        }
        if (e < be.y) {
            float2 v0 = *reinterpret_cast<const float2*>(qb + (unsigned int)col[e]);
            ax += v0.x; ay += v0.y;
        }
    }
#pragma unroll
    for (int m = 1; m <= 8; m <<= 1) {
        ax += __shfl_xor(ax, m);
        ay += __shfl_xor(ay, m);
    }
    if (slot == 0) {
        if (valid) {
            float2 self = qz[node];
            float di = dinv[node];
            sh[li] = make_float2(di * (ax + self.x), di * (ay + self.y));
            sg[li] = batch[node];
        } else {
            sh[li] = make_float2(0.f, 0.f);
            sg[li] = -1;
        }
    }
    __syncthreads();
    if (tid < 2) {
        float s = 0.f;
        int gp = -1;
        for (int w = 0; w < 16; ++w) {
            int g = sg[w];
            if (g < 0) continue;
            if (g != gp) {
                if (gp >= 0) atomicAdd(&pooled2[gp * 2 + tid], s);
                s = 0.f;
                gp = g;
            }
            s += (tid == 0) ? sh[w].x : sh[w].y;
        }
        if (gp >= 0) atomicAdd(&pooled2[gp * 2 + tid], s);
    }
}

// ---------- head: counts via binary search, z = pooled2/cnt + zc, softmax over graphs ----------
__global__ __launch_bounds__(512) void head_kernel(const float* __restrict__ pooled2,
                                                   const int* __restrict__ batch,
                                                   const float* __restrict__ zc,
                                                   float* __restrict__ out, int N) {
    __shared__ float red[512];
    int tid = threadIdx.x;
    int g = tid;
    auto lb = [&](int key) {
        int l = 0, r = N;
        while (l < r) { int m = (l + r) >> 1; if (batch[m] < key) l = m + 1; else r = m; }
        return l;
    };
    int cnt = lb(g + 1) - lb(g);
    float cn = fmaxf((float)cnt, 1.f);
    float z0 = pooled2[g * 2 + 0] / cn + zc[0];
    float z1 = pooled2[g * 2 + 1] / cn + zc[1];

    red[tid] = z0; __syncthreads();
    for (int s = 256; s > 0; s >>= 1) { if (tid < s) red[tid] = fmaxf(red[tid], red[tid + s]); __syncthreads(); }
    float m0 = red[0]; __syncthreads();
    float e0 = expf(z0 - m0);
    red[tid] = e0; __syncthreads();
    for (int s = 256; s > 0; s >>= 1) { if (tid < s) red[tid] += red[tid + s]; __syncthreads(); }
    float s0 = red[0]; __syncthreads();
    out[g * 2 + 0] = e0 / s0;

    red[tid] = z1; __syncthreads();
    for (int s = 256; s > 0; s >>= 1) { if (tid < s) red[tid] = fmaxf(red[tid], red[tid + s]); __syncthreads(); }
    float m1 = red[0]; __syncthreads();
    float e1 = expf(z1 - m1);
    red[tid] = e1; __syncthreads();
    for (int s = 256; s > 0; s >>= 1) { if (tid < s) red[tid] += red[tid + s]; __syncthreads(); }
    float s1 = red[0]; __syncthreads();
    out[g * 2 + 1] = e1 / s1;
}

// ---------- launch ----------
extern "C" void kernel_launch(void* const* d_in, const int* in_sizes, int n_in,
                              void* d_out, int out_size, void* d_ws, size_t ws_size,
                              hipStream_t stream) {
    const float* x   = (const float*)d_in[0];
    const int*   ei  = (const int*)d_in[1];
    const int*   bat = (const int*)d_in[2];
    const float* W1  = (const float*)d_in[3];
    const float* b1  = (const float*)d_in[4];
    const float* W2  = (const float*)d_in[5];
    const float* b2  = (const float*)d_in[6];
    const float* Wl1 = (const float*)d_in[7];
    const float* bl1 = (const float*)d_in[8];
    const float* Wl2 = (const float*)d_in[9];
    const float* bl2 = (const float*)d_in[10];
    float* out = (float*)d_out;

    const int N = N_NODES, E = N_EDGES;
    const int* src = ei;
    const int* dst = ei + E;

    size_t o = 0;
    auto alloc = [&](size_t bytes) {
        void* p = (char*)d_ws + o;
        o += (bytes + 255) / 256 * 256;
        return p;
    };
    int*           cursor  = (int*)alloc((size_t)NB * 4);
    unsigned int*  pairs   = (unsigned int*)alloc((size_t)NB * SLACK * 4 + 4096);
    int*           col     = (int*)alloc((size_t)NB * SLACK * 4 + 4096);
    int2*          bele    = (int2*)alloc((size_t)N * 8);
    float*         dinv    = (float*)alloc((size_t)N * 4);
    unsigned char* T       = (unsigned char*)alloc((size_t)N * 64);
    float2*        qz      = (float2*)alloc((size_t)N * 8);
    float*         Wz      = (float*)alloc(128 * 4);
    float*         zc      = (float*)alloc(2 * 4);
    float*         pooled2 = (float*)alloc((size_t)N_GRAPHS * 2 * 4);

    // setup: cursors, Wz/zc fold, pooled2 zero (single dispatch)
    setup_kernel<<<1, 256, 0, stream>>>(W2, b2, Wl1, bl1, Wl2, bl2, cursor, Wz, zc, pooled2);

    // CSR build: fused single-pass scatter -> single-pass reg-stash bucket sort
    scatter3_kernel<<<SBLOCKS, 256, 0, stream>>>(src, dst, cursor, pairs, E);
    bucket_kernel<<<NB, 256, 0, stream>>>(pairs, cursor, col, bele, dinv, N);

    // layer 1: U = fp8(dinv * (x @ W1)) ; qz = dinv * relu(dinv*(sum+self)+b1) @ Wz
    lin_kernel<128><<<N / 32, 256, 0, stream>>>(x, W1, dinv, T);
    agg1_kernel<<<(N + 3) / 4, 256, 0, stream>>>(T, bele, col, dinv, b1, Wz, qz, N);

    // layer 2 collapsed to 2 features + fused pooling (16 lanes/node CSR walk)
    agg2q_kernel<<<(N + 15) / 16, 256, 0, stream>>>(qz, bele, col, dinv, pooled2, bat, N);

    // head: counts + mean + const + softmax over graphs
    head_kernel<<<1, 512, 0, stream>>>(pooled2, bat, zc, out, N);
}